// Round 18
// baseline (249.989 us; speedup 1.0000x reference)
//
#include <hip/hip_runtime.h>

#define T_DIM 1024
#define D_DIM 512
#define M_CODES 2048
#define NT 32768            // 32*1024 query rows
#define TOTAL 16777216      // NT*D_DIM

typedef float f32x4 __attribute__((ext_vector_type(4)));
typedef unsigned int u32;
typedef unsigned long long u64;

// ---- workspace layout (bytes) ----
#define WS_MU    0                        // 16384 f32
#define WS_S     65536                    // 16384 f32
#define WS_CE    131072                   // 2048 f32
#define WS_KEYS  139264                   // 32768 u64
#define WS_EB    401408                   // 2048*512 fp8 (rounded codebook, 1MB)
#define WS_HIST  (401408 + 1048576)       // 2048 u32
#define WS_LPART (WS_HIST + 8192)         // 8192 f32 per-block loss partials

// async global->LDS, 16B per lane; global src per-lane, LDS dst wave-uniform
__device__ __forceinline__ void gload16(const void* g, void* l) {
    __builtin_amdgcn_global_load_lds(
        (const __attribute__((address_space(1))) u32*)g,
        (__attribute__((address_space(3))) u32*)l, 16, 0, 0);
}

__device__ __forceinline__ float block_reduce_sum_256(float v) {
    #pragma unroll
    for (int s = 32; s; s >>= 1) v += __shfl_xor(v, s, 64);
    __shared__ float ls[4];
    int w = threadIdx.x >> 6;
    if ((threadIdx.x & 63) == 0) ls[w] = v;
    __syncthreads();
    float r = (ls[0] + ls[1]) + (ls[2] + ls[3]);
    __syncthreads();
    return r;
}

// pack 4 floats -> 4 fp8 e4m3 (OCP, RNE)
__device__ __forceinline__ u32 pk_fp8x4(float a, float b, float c, float d) {
    u32 w = __builtin_amdgcn_cvt_pk_fp8_f32(a, b, 0, false);
    w = __builtin_amdgcn_cvt_pk_fp8_f32(c, d, w, true);
    return w;
}

// monotone float->uint (total order incl. negatives)
__device__ __forceinline__ u32 mono(float f) {
    u32 u = __float_as_uint(f);
    return u ^ (0x80000000u | (u32)((int)u >> 31));
}

// eb K-permutation (pack-time): within each 32B k-block of row r, 8B sub-slot
// s stores orig sub-slot s ^ ((r>>2)&3). Read-side XOR (xfg) cancels it and
// makes b64 LDS reads bank-conflict-free (verified R13: 0 conflicts).
__device__ __forceinline__ int pk_dest(int d, int row) {
    return (d & ~31) | ((((d >> 3) & 3) ^ ((row >> 2) & 3)) << 3) | (d & 7);
}

// ---- instance-norm stats over T per (n,d): mu, s=std+eps ----
__global__ void stats_kernel(const float* __restrict__ x,
                             float* __restrict__ mu_o, float* __restrict__ s_o) {
    int n = blockIdx.y;
    int lane = threadIdx.x & 63;
    int d = blockIdx.x * 64 + lane;
    int tg = threadIdx.x >> 6;
    const float* xp = x + (size_t)n * (T_DIM * D_DIM) + d;
    float sum = 0.f, sq = 0.f;
    int t0 = tg * 256;
    for (int it = 0; it < 256; ++it) {
        float v = xp[(size_t)(t0 + it) * D_DIM];
        sum += v; sq += v * v;
    }
    __shared__ float ssum[4][64], ssq[4][64];
    ssum[tg][lane] = sum;
    ssq[tg][lane] = sq;
    __syncthreads();
    if (threadIdx.x < 64) {
        int l = threadIdx.x;
        float s1 = (ssum[0][l] + ssum[1][l]) + (ssum[2][l] + ssum[3][l]);
        float q1 = (ssq[0][l] + ssq[1][l]) + (ssq[2][l] + ssq[3][l]);
        float mu = s1 * (1.0f / 1024.0f);
        float var = (q1 - 1024.0f * mu * mu) * (1.0f / 1023.0f);
        var = fmaxf(var, 0.0f);
        float sd = sqrtf(var) + 1e-5f;
        int nd = n * D_DIM + blockIdx.x * 64 + l;
        mu_o[nd] = mu; s_o[nd] = sd;
    }
}

// ---- codebook prep: emb_n -> fp8 (K-permuted), ce = exact sum(emb_n^2) ----
__global__ void codebook_kernel(const float* __restrict__ emb,
                                unsigned char* __restrict__ eb, float* __restrict__ ce) {
    int j = blockIdx.x;
    int d = threadIdx.x * 2;
    float2 e = *(const float2*)&emb[(size_t)j * D_DIM + d];
    float sq = e.x * e.x + e.y * e.y;
    float norm2 = block_reduce_sum_256(sq);
    float den = sqrtf(norm2) + 1e-4f;
    float en0 = e.x / den, en1 = e.y / den;
    u32 w = __builtin_amdgcn_cvt_pk_fp8_f32(en0, en1, 0, false);
    *(unsigned short*)&eb[(size_t)j * D_DIM + pk_dest(d, j)] =
        (unsigned short)(w & 0xFFFF);
    float cep = en0 * en0 + en1 * en1;      // ce from EXACT emb_n (matches ref)
    float cesum = block_reduce_sum_256(cep);
    if (threadIdx.x == 0) ce[j] = cesum;
}

// ---- z = (x-mu)/s exact fp32; store z as fp8, LINEAR layout (A is read
// per-lane from global in gemm; no LDS staging -> no permutation needed) ----
__global__ void pack_kernel(const float* __restrict__ x, const float* __restrict__ mu,
                            const float* __restrict__ s, unsigned char* __restrict__ zq) {
    int i = blockIdx.x * 4 + (threadIdx.x >> 6);
    int lane = threadIdx.x & 63;
    int n = i >> 10;
    const float* xp = x + (size_t)i * D_DIM;
    const float* mp = mu + n * D_DIM;
    const float* sp = s + n * D_DIM;
    #pragma unroll
    for (int c = 0; c < 2; ++c) {
        int d = c * 256 + lane * 4;
        float4 xv = *(const float4*)&xp[d];
        float4 mv = *(const float4*)&mp[d];
        float4 sv = *(const float4*)&sp[d];
        float z0 = (xv.x - mv.x) / sv.x;
        float z1 = (xv.y - mv.y) / sv.y;
        float z2 = (xv.z - mv.z) / sv.z;
        float z3 = (xv.w - mv.w) / sv.w;
        *(u32*)&zq[(size_t)i * D_DIM + d] = pk_fp8x4(z0, z1, z2, z3);
    }
}

// ---- MFMA fp8 GEMM + argmin, persistent-B / barrier-free K-loop ----
// 256 blocks (1/CU): block owns one 256-code B-tile, resident in LDS (128KB),
// loaded once (single barrier). Then 8 waves (4Mx2N, 64x128 out each) run
// INDEPENDENT K-loops over 4 m-tiles of 256 rows: A b64 frags per-lane from
// global (L2/L3-resident, 2-step reg prefetch), B b64 frags from LDS (1-step
// prefetch, xfg conflict-free). No barriers -> no drain stalls (R12-R17's
// invariant cost). MFMA sequence/K-order identical to R13 -> same keys.
__global__ __launch_bounds__(512, 2) void gemm_argmin(
    const unsigned char* __restrict__ zq, const unsigned char* __restrict__ eb,
    const float* __restrict__ ce, u64* __restrict__ keys) {
    __shared__ long bsm[16384];               // 256 rows x 512B = 128KB
    int tid = threadIdx.x;
    int bid = blockIdx.x;
    // bid = q*8 + x (x ~ XCD): n cycles fastest within an XCD -> the 8 blocks
    // sharing an m-chunk sit on one XCD and reuse A from its L2.
    int x = bid & 7;
    int q = bid >> 3;
    int n0 = (q & 7) * 256;                   // code tile (8 n-tiles)
    int mc = x * 4 + (q >> 3);                // m-chunk 0..31 (1024 rows each)

    int w = tid >> 6, l = tid & 63;
    int wm = (w >> 1) * 64;                   // 4 M-groups of 64
    int wn = (w & 1) * 128;                   // 2 N-groups of 128
    int fr = l & 15, fg = l >> 4;
    int xfg = fg ^ ((fr >> 2) & 3);           // cancels eb's pk_dest

    // ---- load B-tile once: wave w stages rows 32w..32w+31 (16 x gload16) ----
    #pragma unroll
    for (int k = 0; k < 16; ++k)
        gload16(eb + (size_t)(n0 + 32 * w + 2 * k) * D_DIM + l * 16,
                &bsm[(32 * w + 2 * k) * 64]);
    __syncthreads();                          // drains vmcnt; only barrier

    #pragma unroll 1
    for (int mt = 0; mt < 4; ++mt) {
        int m0 = mc * 1024 + mt * 256;
        f32x4 acc[4][8];
        #pragma unroll
        for (int a = 0; a < 4; ++a)
            #pragma unroll
            for (int b = 0; b < 8; ++b) acc[a][b] = (f32x4)0.0f;

        const unsigned char* abase[4];
        long abuf[2][4];                      // A prefetch: steps t, t+1
        #pragma unroll
        for (int i = 0; i < 4; ++i) {
            abase[i] = zq + (size_t)(m0 + wm + i * 16 + fr) * D_DIM + fg * 8;
            abuf[0][i] = *(const long*)(abase[i]);
            abuf[1][i] = *(const long*)(abase[i] + 32);
        }
        long bbuf[2][8];                      // B prefetch: step t
        #pragma unroll
        for (int j = 0; j < 8; ++j)
            bbuf[0][j] = bsm[(wn + j * 16 + fr) * 64 + xfg];

        #pragma unroll
        for (int t = 0; t < 16; ++t) {
            int cs = t & 1, ns = cs ^ 1;
            if (t < 15) {
                #pragma unroll
                for (int j = 0; j < 8; ++j)
                    bbuf[ns][j] = bsm[(wn + j * 16 + fr) * 64 + (t + 1) * 4 + xfg];
            }
            long av[4];
            #pragma unroll
            for (int i = 0; i < 4; ++i) av[i] = abuf[cs][i];
            if (t < 14) {
                #pragma unroll
                for (int i = 0; i < 4; ++i)
                    abuf[cs][i] = *(const long*)(abase[i] + (t + 2) * 32);
            }
            #pragma unroll
            for (int mb = 0; mb < 4; ++mb)
                #pragma unroll
                for (int nb = 0; nb < 8; ++nb)
                    acc[mb][nb] = __builtin_amdgcn_mfma_f32_16x16x32_fp8_fp8(
                        av[mb], bbuf[cs][nb], acc[mb][nb], 0, 0, 0);
        }

        // epilogue: argmin of (ce_j - 2*dot) [cz constant over j: dropped]
        #pragma unroll
        for (int mb = 0; mb < 4; ++mb) {
            #pragma unroll
            for (int r = 0; r < 4; ++r) {
                int qrow = m0 + wm + mb * 16 + fg * 4 + r;
                u64 best = ~0ULL;
                #pragma unroll
                for (int nb = 0; nb < 8; ++nb) {
                    int j = n0 + wn + nb * 16 + fr;
                    float dist = ce[j] - 2.0f * acc[mb][nb][r];
                    u64 key = ((u64)mono(dist) << 32) | (unsigned)j;
                    if (key < best) best = key;
                }
                #pragma unroll
                for (int sft = 1; sft < 16; sft <<= 1) {
                    u64 o = __shfl_xor(best, sft, 64);
                    if (o < best) best = o;
                }
                if (fr == 0) atomicMin(keys + qrow, best);
            }
        }
    }
}

// ---- gather + STE output + loss partials + histogram (1 wave per row) ----
// Reads x/mu/s (NOT zq: out writes alias zq's d_out staging -> cross-block
// race, R14 lesson). Exact-fp32 z for output and loss.
__global__ void output_kernel(const float* __restrict__ x, const float* __restrict__ mu,
                              const float* __restrict__ s, const float* __restrict__ emb,
                              const u64* __restrict__ keys,
                              float* __restrict__ out, float* __restrict__ loss_part,
                              unsigned* __restrict__ hist) {
    int i = blockIdx.x * 4 + (threadIdx.x >> 6);
    int lane = threadIdx.x & 63;
    int n = i >> 10;
    unsigned idx = (unsigned)(keys[i] & 0xFFFFFFFFULL);
    float lsum = 0.f;
    #pragma unroll
    for (int c = 0; c < 2; ++c) {
        int d = c * 256 + lane * 4;
        float4 xv = *(const float4*)&x[(size_t)i * D_DIM + d];
        float4 mv = *(const float4*)&mu[n * D_DIM + d];
        float4 sv = *(const float4*)&s[n * D_DIM + d];
        float4 ev = *(const float4*)&emb[(size_t)idx * D_DIM + d];
        float z0 = (xv.x - mv.x) / sv.x;
        float z1 = (xv.y - mv.y) / sv.y;
        float z2 = (xv.z - mv.z) / sv.z;
        float z3 = (xv.w - mv.w) / sv.w;
        float o0 = ((z0 + (ev.x - z0)) + ev.x) * 0.5f;
        float o1 = ((z1 + (ev.y - z1)) + ev.y) * 0.5f;
        float o2 = ((z2 + (ev.z - z2)) + ev.z) * 0.5f;
        float o3 = ((z3 + (ev.w - z3)) + ev.w) * 0.5f;
        *(float4*)&out[(size_t)i * D_DIM + d] = make_float4(o0, o1, o2, o3);
        lsum += (z0 - ev.x) * (z0 - ev.x) + (z1 - ev.y) * (z1 - ev.y)
              + (z2 - ev.z) * (z2 - ev.z) + (z3 - ev.w) * (z3 - ev.w);
    }
    #pragma unroll
    for (int sft = 32; sft; sft >>= 1) lsum += __shfl_xor(lsum, sft, 64);
    __shared__ float ls[4];
    if (lane == 0) {
        ls[threadIdx.x >> 6] = lsum;
        atomicAdd(&hist[idx], 1u);   // scattered over 2048 bins: cheap
    }
    __syncthreads();
    if (threadIdx.x == 0)
        loss_part[blockIdx.x] = (ls[0] + ls[1]) + (ls[2] + ls[3]);
}

// ---- scalars: loss mean (from partials) + perplexity ----
__global__ void final_kernel(const unsigned* __restrict__ hist,
                             const float* __restrict__ loss_part, float* __restrict__ out) {
    float h = 0.f;
    for (int b = threadIdx.x; b < M_CODES; b += 256) {
        float p = (float)hist[b] * (1.0f / 32768.0f);
        h += p * logf(p + 1e-10f);
    }
    h = block_reduce_sum_256(h);
    float lsum = 0.f;
    for (int b = threadIdx.x; b < NT / 4; b += 256) lsum += loss_part[b];
    lsum = block_reduce_sum_256(lsum);
    if (threadIdx.x == 0) {
        out[TOTAL] = lsum * (1.0f / 16777216.0f);
        out[TOTAL + 1] = expf(-h);
    }
}

extern "C" void kernel_launch(void* const* d_in, const int* in_sizes, int n_in,
                              void* d_out, int out_size, void* d_ws, size_t ws_size,
                              hipStream_t stream) {
    (void)in_sizes; (void)n_in; (void)out_size; (void)ws_size;
    const float* x = (const float*)d_in[0];
    const float* emb = (const float*)d_in[1];
    float* out = (float*)d_out;
    char* ws = (char*)d_ws;
    float* mu   = (float*)(ws + WS_MU);
    float* s    = (float*)(ws + WS_S);
    float* ce   = (float*)(ws + WS_CE);
    u64* keys = (u64*)(ws + WS_KEYS);
    unsigned char* eb = (unsigned char*)(ws + WS_EB);
    unsigned* hist = (unsigned*)(ws + WS_HIST);
    float* loss_part = (float*)(ws + WS_LPART);
    // z fp8 staged in d_out (16MB); output_kernel does NOT read it (race-safe)
    unsigned char* zq = (unsigned char*)d_out;

    (void)hipMemsetAsync(ws + WS_KEYS, 0xFF, 262144, stream);
    (void)hipMemsetAsync(ws + WS_HIST, 0x00, 8192, stream);

    stats_kernel<<<dim3(8, 32), 256, 0, stream>>>(x, mu, s);
    codebook_kernel<<<M_CODES, 256, 0, stream>>>(emb, eb, ce);
    pack_kernel<<<NT / 4, 256, 0, stream>>>(x, mu, s, zq);
    gemm_argmin<<<256, 512, 0, stream>>>(zq, eb, ce, keys);
    output_kernel<<<NT / 4, 256, 0, stream>>>(x, mu, s, emb, keys, out, loss_part, hist);
    final_kernel<<<1, 256, 0, stream>>>(hist, loss_part, out);
}

// Round 19
// 163.434 us; speedup vs baseline: 1.5296x; 1.5296x over previous
//
#include <hip/hip_runtime.h>

#define T_DIM 1024
#define D_DIM 512
#define M_CODES 2048
#define NT 32768            // 32*1024 query rows
#define TOTAL 16777216      // NT*D_DIM

typedef float f32x4 __attribute__((ext_vector_type(4)));
typedef unsigned int u32;
typedef unsigned long long u64;

// ---- workspace layout (bytes) ----
#define WS_MU    0                        // 16384 f32
#define WS_S     65536                    // 16384 f32
#define WS_CE    131072                   // 2048 f32
#define WS_KEYS  139264                   // 32768 u64
#define WS_EB    401408                   // 2048*512 fp8 (rounded codebook, 1MB)
#define WS_HIST  (401408 + 1048576)       // 2048 u32
#define WS_LPART (WS_HIST + 8192)         // 8192 f32 per-block loss partials

// async global->LDS, 16B per lane; dst wave-uniform base (HW adds lane*16)
__device__ __forceinline__ void gload16(const void* g, void* l) {
    __builtin_amdgcn_global_load_lds(
        (const __attribute__((address_space(1))) u32*)g,
        (__attribute__((address_space(3))) u32*)l, 16, 0, 0);
}

__device__ __forceinline__ float block_reduce_sum_256(float v) {
    #pragma unroll
    for (int s = 32; s; s >>= 1) v += __shfl_xor(v, s, 64);
    __shared__ float ls[4];
    int w = threadIdx.x >> 6;
    if ((threadIdx.x & 63) == 0) ls[w] = v;
    __syncthreads();
    float r = (ls[0] + ls[1]) + (ls[2] + ls[3]);
    __syncthreads();
    return r;
}

// pack 4 floats -> 4 fp8 e4m3 (OCP, RNE)
__device__ __forceinline__ u32 pk_fp8x4(float a, float b, float c, float d) {
    u32 w = __builtin_amdgcn_cvt_pk_fp8_f32(a, b, 0, false);
    w = __builtin_amdgcn_cvt_pk_fp8_f32(c, d, w, true);
    return w;
}

// monotone float->uint (total order incl. negatives)
__device__ __forceinline__ u32 mono(float f) {
    u32 u = __float_as_uint(f);
    return u ^ (0x80000000u | (u32)((int)u >> 31));
}

// K-layout permutation baked at pack time: within each 32B k-block of row r,
// 8B sub-slot s stores orig sub-slot s ^ ((r>>2)&3). Read side XORs the same
// -> cancels (MFMA inputs identical), and b64 fragment reads are
// bank-conflict-free at 32B row stride (verified R13: 0 conflicts).
__device__ __forceinline__ int pk_dest(int d, int row) {
    return (d & ~31) | ((((d >> 3) & 3) ^ ((row >> 2) & 3)) << 3) | (d & 7);
}

// ---- instance-norm stats over T per (n,d): mu, s=std+eps ----
__global__ void stats_kernel(const float* __restrict__ x,
                             float* __restrict__ mu_o, float* __restrict__ s_o) {
    int n = blockIdx.y;
    int lane = threadIdx.x & 63;
    int d = blockIdx.x * 64 + lane;
    int tg = threadIdx.x >> 6;
    const float* xp = x + (size_t)n * (T_DIM * D_DIM) + d;
    float sum = 0.f, sq = 0.f;
    int t0 = tg * 256;
    for (int it = 0; it < 256; ++it) {
        float v = xp[(size_t)(t0 + it) * D_DIM];
        sum += v; sq += v * v;
    }
    __shared__ float ssum[4][64], ssq[4][64];
    ssum[tg][lane] = sum;
    ssq[tg][lane] = sq;
    __syncthreads();
    if (threadIdx.x < 64) {
        int l = threadIdx.x;
        float s1 = (ssum[0][l] + ssum[1][l]) + (ssum[2][l] + ssum[3][l]);
        float q1 = (ssq[0][l] + ssq[1][l]) + (ssq[2][l] + ssq[3][l]);
        float mu = s1 * (1.0f / 1024.0f);
        float var = (q1 - 1024.0f * mu * mu) * (1.0f / 1023.0f);
        var = fmaxf(var, 0.0f);
        float sd = sqrtf(var) + 1e-5f;
        int nd = n * D_DIM + blockIdx.x * 64 + l;
        mu_o[nd] = mu; s_o[nd] = sd;
    }
}

// ---- codebook prep: emb_n -> fp8 (K-permuted), ce = exact sum(emb_n^2) ----
__global__ void codebook_kernel(const float* __restrict__ emb,
                                unsigned char* __restrict__ eb, float* __restrict__ ce) {
    int j = blockIdx.x;
    int d = threadIdx.x * 2;
    float2 e = *(const float2*)&emb[(size_t)j * D_DIM + d];
    float sq = e.x * e.x + e.y * e.y;
    float norm2 = block_reduce_sum_256(sq);
    float den = sqrtf(norm2) + 1e-4f;
    float en0 = e.x / den, en1 = e.y / den;
    u32 w = __builtin_amdgcn_cvt_pk_fp8_f32(en0, en1, 0, false);
    *(unsigned short*)&eb[(size_t)j * D_DIM + pk_dest(d, j)] =
        (unsigned short)(w & 0xFFFF);
    float cep = en0 * en0 + en1 * en1;      // ce from EXACT emb_n (matches ref)
    float cesum = block_reduce_sum_256(cep);
    if (threadIdx.x == 0) ce[j] = cesum;
}

// ---- z = (x-mu)/s exact fp32; store z as fp8 (K-permuted). No cz needed:
// cz is constant over j -> argmin-invariant. ----
__global__ void pack_kernel(const float* __restrict__ x, const float* __restrict__ mu,
                            const float* __restrict__ s, unsigned char* __restrict__ zq) {
    int i = blockIdx.x * 4 + (threadIdx.x >> 6);
    int lane = threadIdx.x & 63;
    int n = i >> 10;
    const float* xp = x + (size_t)i * D_DIM;
    const float* mp = mu + n * D_DIM;
    const float* sp = s + n * D_DIM;
    #pragma unroll
    for (int c = 0; c < 2; ++c) {
        int d = c * 256 + lane * 4;
        float4 xv = *(const float4*)&xp[d];
        float4 mv = *(const float4*)&mp[d];
        float4 sv = *(const float4*)&sp[d];
        float z0 = (xv.x - mv.x) / sv.x;
        float z1 = (xv.y - mv.y) / sv.y;
        float z2 = (xv.z - mv.z) / sv.z;
        float z3 = (xv.w - mv.w) / sv.w;
        *(u32*)&zq[(size_t)i * D_DIM + pk_dest(d, i)] = pk_fp8x4(z0, z1, z2, z3);
    }
}

// ---- MFMA fp8 GEMM + argmin, BK=64 / 8-step / 3-buffer pipeline ----
// Tile 256x256, BK=64 (8 steps x 32KB), 8 waves (4Mx2N), 3 LDS bufs (96KB).
// Each 32B k-plane is a separate 256-row x 32B LDS plane (row stride 32B =
// R13's verified conflict-free b64 pattern). Deconflates R12: BK=64 was only
// slow due to bank conflicts, now zero. 4 gloads/wave/step; vmcnt(4) steady.
// K-accum order per (mb,nb) is plane0,plane1 = sequential -> keys identical.
__global__ __launch_bounds__(512, 2) void gemm_argmin(
    const unsigned char* __restrict__ zq, const unsigned char* __restrict__ eb,
    const float* __restrict__ ce, u64* __restrict__ keys) {
    __shared__ long smem[3][4096];            // 3 x {A0|A1|B0|B1}[1024 u64]
    int tid = threadIdx.x;
    int bid = blockIdx.x;
    // XCD-chunked (1024%8==0): per XCD n varies fastest -> A-tile L2 reuse.
    int swz = (bid & 7) * 128 + (bid >> 3);
    int n0 = (swz & 7) * 256;                 // code tile (8 n-tiles)
    int m0 = (swz >> 3) * 256;                // query-row tile (128 m-tiles)

    f32x4 acc[4][8];
    #pragma unroll
    for (int a = 0; a < 4; ++a)
        #pragma unroll
        for (int b = 0; b < 8; ++b) acc[a][b] = (f32x4)0.0f;

    int w = tid >> 6, l = tid & 63;
    int wm = (w >> 1) * 64;                   // 4 M-groups of 64
    int wn = (w & 1) * 128;                   // 2 N-groups of 128
    int fr = l & 15, fg = l >> 4;
    int xfg = fg ^ ((fr >> 2) & 3);           // read-side XOR (cancels packing)

    // staging: per wave per step 4 gload16 (A planes 0/1, B planes 0/1);
    // wave w covers rows 32w..32w+31, lane l: row +(l>>1), 16B-half (l&1).
    int rS = 32 * w + (l >> 1);
    int hS = (l & 1) * 16;
    size_t srcA = (size_t)(m0 + rS) * D_DIM + hS;
    size_t srcB = (size_t)(n0 + rS) * D_DIM + hS;

    #define STAGE(buf, t) do {                                                    \
        gload16(zq + srcA + (t) * 64,      &smem[buf][       w * 128]);           \
        gload16(zq + srcA + (t) * 64 + 32, &smem[buf][1024 + w * 128]);           \
        gload16(eb + srcB + (t) * 64,      &smem[buf][2048 + w * 128]);           \
        gload16(eb + srcB + (t) * 64 + 32, &smem[buf][3072 + w * 128]);           \
    } while (0)

    STAGE(0, 0);
    STAGE(1, 1);
    asm volatile("s_waitcnt vmcnt(4)" ::: "memory");   // buf0's 4 landed
    __builtin_amdgcn_s_barrier();
    __builtin_amdgcn_sched_barrier(0);

    int rd = 0, wr = 2;
    for (int t = 0; t < 8; ++t) {
        if (t <= 5) STAGE(wr, t + 2);
        long a0[4], a1[4], b0[8], b1[8];
        #pragma unroll
        for (int i = 0; i < 4; ++i) {
            int ri = (wm + i * 16 + fr) * 4 + xfg;
            a0[i] = smem[rd][ri];
            a1[i] = smem[rd][1024 + ri];
        }
        #pragma unroll
        for (int j = 0; j < 8; ++j) {
            int rj = (wn + j * 16 + fr) * 4 + xfg;
            b0[j] = smem[rd][2048 + rj];
            b1[j] = smem[rd][3072 + rj];
        }
        __builtin_amdgcn_s_setprio(1);
        #pragma unroll
        for (int mb = 0; mb < 4; ++mb)
            #pragma unroll
            for (int nb = 0; nb < 8; ++nb) {
                acc[mb][nb] = __builtin_amdgcn_mfma_f32_16x16x32_fp8_fp8(
                    a0[mb], b0[nb], acc[mb][nb], 0, 0, 0);
                acc[mb][nb] = __builtin_amdgcn_mfma_f32_16x16x32_fp8_fp8(
                    a1[mb], b1[nb], acc[mb][nb], 0, 0, 0);
            }
        __builtin_amdgcn_s_setprio(0);
        if (t < 7) {
            // counted: buf t+1's 4 landed; buf t+2's 4 stay in flight
            if (t <= 5) asm volatile("s_waitcnt vmcnt(4)" ::: "memory");
            else        asm volatile("s_waitcnt vmcnt(0)" ::: "memory");
            __builtin_amdgcn_s_barrier();
            __builtin_amdgcn_sched_barrier(0);
        }
        if (++rd == 3) rd = 0;
        if (++wr == 3) wr = 0;
    }
    #undef STAGE

    // epilogue: argmin of (ce_j - 2*dot)  [cz dropped: constant over j]
    #pragma unroll
    for (int mb = 0; mb < 4; ++mb) {
        #pragma unroll
        for (int r = 0; r < 4; ++r) {
            int q = m0 + wm + mb * 16 + fg * 4 + r;
            u64 best = ~0ULL;
            #pragma unroll
            for (int nb = 0; nb < 8; ++nb) {
                int j = n0 + wn + nb * 16 + fr;
                float dist = ce[j] - 2.0f * acc[mb][nb][r];
                u64 key = ((u64)mono(dist) << 32) | (unsigned)j;
                if (key < best) best = key;
            }
            #pragma unroll
            for (int sft = 1; sft < 16; sft <<= 1) {
                u64 o = __shfl_xor(best, sft, 64);
                if (o < best) best = o;
            }
            if (fr == 0) atomicMin(keys + q, best);
        }
    }
}

// ---- gather + STE output + loss partials + histogram (1 wave per row) ----
// Reads x/mu/s (NOT zq: out writes alias zq's d_out staging -> cross-block
// race, R14 lesson). Exact-fp32 z for output and loss.
__global__ void output_kernel(const float* __restrict__ x, const float* __restrict__ mu,
                              const float* __restrict__ s, const float* __restrict__ emb,
                              const u64* __restrict__ keys,
                              float* __restrict__ out, float* __restrict__ loss_part,
                              unsigned* __restrict__ hist) {
    int i = blockIdx.x * 4 + (threadIdx.x >> 6);
    int lane = threadIdx.x & 63;
    int n = i >> 10;
    unsigned idx = (unsigned)(keys[i] & 0xFFFFFFFFULL);
    float lsum = 0.f;
    #pragma unroll
    for (int c = 0; c < 2; ++c) {
        int d = c * 256 + lane * 4;
        float4 xv = *(const float4*)&x[(size_t)i * D_DIM + d];
        float4 mv = *(const float4*)&mu[n * D_DIM + d];
        float4 sv = *(const float4*)&s[n * D_DIM + d];
        float4 ev = *(const float4*)&emb[(size_t)idx * D_DIM + d];
        float z0 = (xv.x - mv.x) / sv.x;
        float z1 = (xv.y - mv.y) / sv.y;
        float z2 = (xv.z - mv.z) / sv.z;
        float z3 = (xv.w - mv.w) / sv.w;
        float o0 = ((z0 + (ev.x - z0)) + ev.x) * 0.5f;
        float o1 = ((z1 + (ev.y - z1)) + ev.y) * 0.5f;
        float o2 = ((z2 + (ev.z - z2)) + ev.z) * 0.5f;
        float o3 = ((z3 + (ev.w - z3)) + ev.w) * 0.5f;
        *(float4*)&out[(size_t)i * D_DIM + d] = make_float4(o0, o1, o2, o3);
        lsum += (z0 - ev.x) * (z0 - ev.x) + (z1 - ev.y) * (z1 - ev.y)
              + (z2 - ev.z) * (z2 - ev.z) + (z3 - ev.w) * (z3 - ev.w);
    }
    #pragma unroll
    for (int sft = 32; sft; sft >>= 1) lsum += __shfl_xor(lsum, sft, 64);
    __shared__ float ls[4];
    if (lane == 0) {
        ls[threadIdx.x >> 6] = lsum;
        atomicAdd(&hist[idx], 1u);   // scattered over 2048 bins: cheap
    }
    __syncthreads();
    if (threadIdx.x == 0)
        loss_part[blockIdx.x] = (ls[0] + ls[1]) + (ls[2] + ls[3]);
}

// ---- scalars: loss mean (from partials) + perplexity ----
__global__ void final_kernel(const unsigned* __restrict__ hist,
                             const float* __restrict__ loss_part, float* __restrict__ out) {
    float h = 0.f;
    for (int b = threadIdx.x; b < M_CODES; b += 256) {
        float p = (float)hist[b] * (1.0f / 32768.0f);
        h += p * logf(p + 1e-10f);
    }
    h = block_reduce_sum_256(h);
    float lsum = 0.f;
    for (int b = threadIdx.x; b < NT / 4; b += 256) lsum += loss_part[b];
    lsum = block_reduce_sum_256(lsum);
    if (threadIdx.x == 0) {
        out[TOTAL] = lsum * (1.0f / 16777216.0f);
        out[TOTAL + 1] = expf(-h);
    }
}

extern "C" void kernel_launch(void* const* d_in, const int* in_sizes, int n_in,
                              void* d_out, int out_size, void* d_ws, size_t ws_size,
                              hipStream_t stream) {
    (void)in_sizes; (void)n_in; (void)out_size; (void)ws_size;
    const float* x = (const float*)d_in[0];
    const float* emb = (const float*)d_in[1];
    float* out = (float*)d_out;
    char* ws = (char*)d_ws;
    float* mu   = (float*)(ws + WS_MU);
    float* s    = (float*)(ws + WS_S);
    float* ce   = (float*)(ws + WS_CE);
    u64* keys = (u64*)(ws + WS_KEYS);
    unsigned char* eb = (unsigned char*)(ws + WS_EB);
    unsigned* hist = (unsigned*)(ws + WS_HIST);
    float* loss_part = (float*)(ws + WS_LPART);
    // z fp8 staged in d_out (16MB); output_kernel does NOT read it (race-safe)
    unsigned char* zq = (unsigned char*)d_out;

    (void)hipMemsetAsync(ws + WS_KEYS, 0xFF, 262144, stream);
    (void)hipMemsetAsync(ws + WS_HIST, 0x00, 8192, stream);

    stats_kernel<<<dim3(8, 32), 256, 0, stream>>>(x, mu, s);
    codebook_kernel<<<M_CODES, 256, 0, stream>>>(emb, eb, ce);
    pack_kernel<<<NT / 4, 256, 0, stream>>>(x, mu, s, zq);
    gemm_argmin<<<1024, 512, 0, stream>>>(zq, eb, ce, keys);
    output_kernel<<<NT / 4, 256, 0, stream>>>(x, mu, s, emb, keys, out, loss_part, hist);
    final_kernel<<<1, 256, 0, stream>>>(hist, loss_part, out);
}